// Round 2
// baseline (568.656 us; speedup 1.0000x reference)
//
#include <hip/hip_runtime.h>
#include <hip/hip_bf16.h>

#define BATCH 512
#define DIM 64
#define KOUT 63

typedef float vf4 __attribute__((ext_vector_type(4)));

// ---------------------------------------------------------------------------
// Kernel 1: bilinear stage.
// grid = dim3(192, 2): blockIdx.x = which*64 + k (k in [0,64)), blockIdx.y = batch half.
// block = 256 threads, 1 batch per thread.
// o[which][b][k] = sum_ij A[b,i] * W[k,i,j] * C[b,j] + bias[k];  o[..][63] = 1.0
// W[k] (16 KiB) staged in LDS once per block, reused by 256 batches.
// ---------------------------------------------------------------------------
__global__ __launch_bounds__(256) void bilinear_kernel(
    const float* __restrict__ x, const float* __restrict__ y, const float* __restrict__ z,
    const float* __restrict__ W1, const float* __restrict__ b1,
    const float* __restrict__ W2, const float* __restrict__ b2,
    const float* __restrict__ W3, const float* __restrict__ b3,
    float* __restrict__ o /* [3][512][64] */) {
    const int which = blockIdx.x >> 6;
    const int k     = blockIdx.x & 63;
    const int b     = blockIdx.y * 256 + threadIdx.x;

    float* outp = o + which * (BATCH * DIM);

    if (k == KOUT) {            // ones column — uniform across block, no divergence
        outp[b * DIM + KOUT] = 1.0f;
        return;
    }

    const float* A  = (which == 2) ? y : x;
    const float* C  = (which == 0) ? y : z;
    const float* W  = ((which == 0) ? W1 : (which == 1) ? W2 : W3) + k * (DIM * DIM);
    const float  bias = ((which == 0) ? b1 : (which == 1) ? b2 : b3)[k];

    __shared__ float sW[DIM * DIM];
    {
        const float4* W4  = (const float4*)W;
        float4*       sW4 = (float4*)sW;
        #pragma unroll
        for (int t = threadIdx.x; t < DIM * DIM / 4; t += 256) sW4[t] = W4[t];
    }
    __syncthreads();

    // y-side row in registers (inner loop fully unrolled -> constant indices)
    float c[DIM];
    {
        const float4* C4 = (const float4*)(C + b * DIM);
        #pragma unroll
        for (int q = 0; q < DIM / 4; q++) {
            float4 v = C4[q];
            c[4 * q + 0] = v.x; c[4 * q + 1] = v.y; c[4 * q + 2] = v.z; c[4 * q + 3] = v.w;
        }
    }

    const float* arow = A + b * DIM;
    const float4* sW4 = (const float4*)sW;
    float acc = bias;
    #pragma unroll 4
    for (int i = 0; i < DIM; i++) {
        float t = 0.0f;
        #pragma unroll
        for (int q = 0; q < DIM / 4; q++) {
            float4 w = sW4[i * (DIM / 4) + q];   // ds_read_b128, wave-uniform broadcast
            t = fmaf(w.x, c[4 * q + 0], t);
            t = fmaf(w.y, c[4 * q + 1], t);
            t = fmaf(w.z, c[4 * q + 2], t);
            t = fmaf(w.w, c[4 * q + 3], t);
        }
        acc = fmaf(arow[i], t, acc);
    }
    outp[b * DIM + k] = acc;
}

// ---------------------------------------------------------------------------
// Kernel 2: triple outer product, 512 MiB streaming write.
// grid = 512 (one block per batch), block = 256.
// out[b, ((i*64+j)*64+k)] = o1[b,i]*o2[b,j]*o3[b,k]
// Non-temporal float4 stores: output is never re-read, keep it out of L2/L3.
// ---------------------------------------------------------------------------
__global__ __launch_bounds__(256) void outer_kernel(
    const float* __restrict__ o /* [3][512][64] */, float* __restrict__ out) {
    const int b = blockIdx.x;
    __shared__ float s1[DIM];
    __shared__ float s2[DIM];
    __shared__ float s3f[DIM];

    const int t = threadIdx.x;
    if (t < 64)        s1[t]        = o[b * DIM + t];
    else if (t < 128)  s2[t - 64]   = o[BATCH * DIM + b * DIM + (t - 64)];
    else if (t < 192)  s3f[t - 128] = o[2 * BATCH * DIM + b * DIM + (t - 128)];
    __syncthreads();

    const vf4* s3 = (const vf4*)s3f;
    vf4* out4 = (vf4*)out + (size_t)b * 65536;

    #pragma unroll 4
    for (int f4 = t; f4 < 65536; f4 += 256) {
        const int k4 = f4 & 15;
        const int j  = (f4 >> 4) & 63;
        const int i  = f4 >> 10;
        const float s = s1[i] * s2[j];
        vf4 v = s3[k4] * s;
        __builtin_nontemporal_store(v, &out4[f4]);
    }
}

extern "C" void kernel_launch(void* const* d_in, const int* in_sizes, int n_in,
                              void* d_out, int out_size, void* d_ws, size_t ws_size,
                              hipStream_t stream) {
    const float* x  = (const float*)d_in[0];
    const float* y  = (const float*)d_in[1];
    const float* z  = (const float*)d_in[2];
    const float* W1 = (const float*)d_in[3];
    const float* b1 = (const float*)d_in[4];
    const float* W2 = (const float*)d_in[5];
    const float* b2 = (const float*)d_in[6];
    const float* W3 = (const float*)d_in[7];
    const float* b3 = (const float*)d_in[8];
    float* out = (float*)d_out;
    float* o   = (float*)d_ws;   // [3][512][64] = 384 KiB

    bilinear_kernel<<<dim3(192, 2), 256, 0, stream>>>(x, y, z, W1, b1, W2, b2, W3, b3, o);
    outer_kernel<<<dim3(BATCH), 256, 0, stream>>>(o, out);
}